// Round 1
// baseline (511.862 us; speedup 1.0000x reference)
//
#include <hip/hip_runtime.h>
#include <math.h>

#define N_NODES 10000
#define N_GRAPHS 64
#define E_RAW 320000
#define E_ALL (E_RAW + N_NODES)   // 330000 edges incl. self-loops
#define NEG_SLOPE 0.2f
#define EPS 1e-16f

// ---------------- generic f32 tiled GEMM: C[M,N] = A[M,K] @ B[K,N] ----------------
// 64x64 tile, BK=64, 256 threads, 4x4 micro-tile. N,K multiples of 64; M guarded.
__global__ __launch_bounds__(256) void gemm_k(const float* __restrict__ A,
                                              const float* __restrict__ B,
                                              float* __restrict__ C,
                                              int M, int N, int K) {
  __shared__ float As[64][68];
  __shared__ float Bs[64][68];
  const int m0 = blockIdx.y * 64, n0 = blockIdx.x * 64;
  const int t = threadIdx.x, tx = t & 15, ty = t >> 4;
  float acc[4][4] = {};
  for (int kk = 0; kk < K; kk += 64) {
    // stage A tile (64 rows x 64 k), coalesced float4
    #pragma unroll
    for (int i = 0; i < 4; i++) {
      int f = t + 256 * i;
      int row = f >> 4, k4 = f & 15;
      float4 v = make_float4(0.f, 0.f, 0.f, 0.f);
      int gr = m0 + row;
      if (gr < M) v = *(const float4*)(A + (size_t)gr * K + kk + 4 * k4);
      *(float4*)(&As[row][4 * k4]) = v;
    }
    // stage B tile (64 k x 64 cols)
    #pragma unroll
    for (int i = 0; i < 4; i++) {
      int f = t + 256 * i;
      int k = f >> 4, c4 = f & 15;
      float4 v = *(const float4*)(B + (size_t)(kk + k) * N + n0 + 4 * c4);
      *(float4*)(&Bs[k][4 * c4]) = v;
    }
    __syncthreads();
    #pragma unroll
    for (int k = 0; k < 64; k++) {
      float4 b = *(const float4*)(&Bs[k][tx * 4]);
      float a0 = As[ty * 4 + 0][k];
      float a1 = As[ty * 4 + 1][k];
      float a2 = As[ty * 4 + 2][k];
      float a3 = As[ty * 4 + 3][k];
      acc[0][0] = fmaf(a0, b.x, acc[0][0]); acc[0][1] = fmaf(a0, b.y, acc[0][1]);
      acc[0][2] = fmaf(a0, b.z, acc[0][2]); acc[0][3] = fmaf(a0, b.w, acc[0][3]);
      acc[1][0] = fmaf(a1, b.x, acc[1][0]); acc[1][1] = fmaf(a1, b.y, acc[1][1]);
      acc[1][2] = fmaf(a1, b.z, acc[1][2]); acc[1][3] = fmaf(a1, b.w, acc[1][3]);
      acc[2][0] = fmaf(a2, b.x, acc[2][0]); acc[2][1] = fmaf(a2, b.y, acc[2][1]);
      acc[2][2] = fmaf(a2, b.z, acc[2][2]); acc[2][3] = fmaf(a2, b.w, acc[2][3]);
      acc[3][0] = fmaf(a3, b.x, acc[3][0]); acc[3][1] = fmaf(a3, b.y, acc[3][1]);
      acc[3][2] = fmaf(a3, b.z, acc[3][2]); acc[3][3] = fmaf(a3, b.w, acc[3][3]);
    }
    __syncthreads();
  }
  #pragma unroll
  for (int i = 0; i < 4; i++) {
    int gr = m0 + ty * 4 + i;
    if (gr < M) {
      float4 v = make_float4(acc[i][0], acc[i][1], acc[i][2], acc[i][3]);
      *(float4*)(C + (size_t)gr * N + n0 + tx * 4) = v;
    }
  }
}

// ---------------- attention logits, layer 1: as1/ad1[n,h] = <xl[n,h,:], a[h,:]> ----------------
__global__ __launch_bounds__(256) void attn1_k(const float* __restrict__ xl,
                                               const float* __restrict__ aS,
                                               const float* __restrict__ aD,
                                               float* __restrict__ as1,
                                               float* __restrict__ ad1) {
  int n = blockIdx.x, t = threadIdx.x;
  int h = t >> 5, lane = t & 31;
  const float* row = xl + (size_t)n * 1024 + h * 128;
  float ps = 0.f, pd = 0.f;
  for (int c = lane; c < 128; c += 32) {
    float v = row[c];
    ps = fmaf(v, aS[h * 128 + c], ps);
    pd = fmaf(v, aD[h * 128 + c], pd);
  }
  #pragma unroll
  for (int off = 16; off; off >>= 1) {
    ps += __shfl_down(ps, off, 32);
    pd += __shfl_down(pd, off, 32);
  }
  if (lane == 0) { as1[n * 8 + h] = ps; ad1[n * 8 + h] = pd; }
}

// ---------------- attention logits, layer 2 (H=1) ----------------
__global__ __launch_bounds__(128) void attn2_k(const float* __restrict__ xl2,
                                               const float* __restrict__ aS,
                                               const float* __restrict__ aD,
                                               float* __restrict__ as2,
                                               float* __restrict__ ad2) {
  int n = blockIdx.x, t = threadIdx.x;
  float v = xl2[(size_t)n * 128 + t];
  float ps = v * aS[t], pd = v * aD[t];
  #pragma unroll
  for (int off = 32; off; off >>= 1) {
    ps += __shfl_down(ps, off);
    pd += __shfl_down(pd, off);
  }
  __shared__ float r1[2], r2[2];
  if ((t & 63) == 0) { r1[t >> 6] = ps; r2[t >> 6] = pd; }
  __syncthreads();
  if (t == 0) { as2[n] = r1[0] + r1[1]; ad2[n] = r2[0] + r2[1]; }
}

// ---------------- CSR build ----------------
__global__ void degree_k(const int* __restrict__ ei, int* __restrict__ deg) {
  int e = blockIdx.x * blockDim.x + threadIdx.x;
  if (e >= E_ALL) return;
  int d = (e < E_RAW) ? ei[E_RAW + e] : (e - E_RAW);
  atomicAdd(&deg[d], 1);
}

__global__ __launch_bounds__(1024) void scan_k(const int* __restrict__ deg,
                                               int* __restrict__ rowptr,
                                               int* __restrict__ wof) {
  __shared__ int part[1024];
  int t = threadIdx.x;
  int base = t * 10;
  int local[10];
  int s = 0;
  #pragma unroll
  for (int i = 0; i < 10; i++) {
    int idx = base + i;
    local[i] = s;
    s += (idx < N_NODES) ? deg[idx] : 0;
  }
  part[t] = s;
  __syncthreads();
  for (int off = 1; off < 1024; off <<= 1) {
    int v = (t >= off) ? part[t - off] : 0;
    __syncthreads();
    part[t] += v;
    __syncthreads();
  }
  int pre = t ? part[t - 1] : 0;
  #pragma unroll
  for (int i = 0; i < 10; i++) {
    int idx = base + i;
    if (idx < N_NODES) {
      int val = pre + local[i];
      rowptr[idx] = val;
      wof[idx] = val;
    }
  }
  if (t == 1023) rowptr[N_NODES] = part[1023];
}

__global__ void fill_k(const int* __restrict__ ei, int* __restrict__ wof,
                       int* __restrict__ csr) {
  int e = blockIdx.x * blockDim.x + threadIdx.x;
  if (e >= E_ALL) return;
  int s, d;
  if (e < E_RAW) { s = ei[e]; d = ei[E_RAW + e]; }
  else           { s = d = e - E_RAW; }
  int pos = atomicAdd(&wof[d], 1);
  csr[pos] = s;
}

// ---------------- layer-1 softmax + aggregation + bias + ELU ----------------
// one block (256 thr) per dst node. H=8, C=128 -> 1024 outputs, 4 per thread.
__global__ __launch_bounds__(256) void agg1_k(const float* __restrict__ xl,
                                              const float* __restrict__ as1,
                                              const float* __restrict__ ad1,
                                              const float* __restrict__ b1,
                                              const int* __restrict__ rowptr,
                                              const int* __restrict__ csr,
                                              float* __restrict__ out) {
  int dst = blockIdx.x, t = threadIdx.x;
  int beg = rowptr[dst], deg = rowptr[dst + 1] - beg;
  int h = t & 7, slot = t >> 3;
  float adh = ad1[dst * 8 + h];
  __shared__ float sred[8][33];
  __shared__ float mh[8], shs[8];
  // pass 1: per-head max of leaky_relu logits
  float pm = -1e30f;
  for (int e = slot; e < deg; e += 32) {
    float v = as1[csr[beg + e] * 8 + h] + adh;
    v = v > 0.f ? v : NEG_SLOPE * v;
    pm = fmaxf(pm, v);
  }
  sred[h][slot] = pm;
  __syncthreads();
  if (t < 8) {
    float m = sred[t][0];
    for (int i = 1; i < 32; i++) m = fmaxf(m, sred[t][i]);
    mh[t] = m;
  }
  __syncthreads();
  float m = mh[h];
  // pass 2: per-head sum of exp
  float ps = 0.f;
  for (int e = slot; e < deg; e += 32) {
    float v = as1[csr[beg + e] * 8 + h] + adh;
    v = v > 0.f ? v : NEG_SLOPE * v;
    ps += __expf(v - m);
  }
  __syncthreads();
  sred[h][slot] = ps;
  __syncthreads();
  if (t < 8) {
    float s2 = 0.f;
    for (int i = 0; i < 32; i++) s2 += sred[t][i];
    shs[t] = 1.0f / (s2 + EPS);
  }
  __syncthreads();
  float inv = shs[h];
  // pass 3: weighted aggregation, 32-edge chunks with alpha staged in LDS
  __shared__ float al[32][8];
  __shared__ int ss[32];
  float acc0 = 0.f, acc1 = 0.f, acc2 = 0.f, acc3 = 0.f;
  int hb = t >> 7;  // head of output o=t (0 or 1); o=t+256r -> head hb+2r
  for (int base = 0; base < deg; base += 32) {
    int nn = min(32, deg - base);
    __syncthreads();
    if (slot < nn) {
      int s = csr[beg + base + slot];
      if (h == 0) ss[slot] = s;
      float v = as1[s * 8 + h] + adh;
      v = v > 0.f ? v : NEG_SLOPE * v;
      al[slot][h] = __expf(v - m) * inv;
    }
    __syncthreads();
    for (int e = 0; e < nn; e++) {
      const float* row = xl + (size_t)ss[e] * 1024;
      acc0 = fmaf(al[e][hb],     row[t],       acc0);
      acc1 = fmaf(al[e][hb + 2], row[t + 256], acc1);
      acc2 = fmaf(al[e][hb + 4], row[t + 512], acc2);
      acc3 = fmaf(al[e][hb + 6], row[t + 768], acc3);
    }
  }
  float accs[4] = {acc0, acc1, acc2, acc3};
  #pragma unroll
  for (int r = 0; r < 4; r++) {
    int o = t + 256 * r;
    float v = accs[r] + b1[o];
    v = v > 0.f ? v : (expf(v) - 1.0f);  // ELU
    out[(size_t)dst * 1024 + o] = v;
  }
}

// ---------------- layer-2 softmax + aggregation + bias + ELU + pooling atomics ----------------
// one block (128 thr) per dst node. H=1, C=128.
__global__ __launch_bounds__(128) void agg2_k(const float* __restrict__ xl2,
                                              const float* __restrict__ as2,
                                              const float* __restrict__ ad2,
                                              const float* __restrict__ b2,
                                              const int* __restrict__ rowptr,
                                              const int* __restrict__ csr,
                                              const int* __restrict__ batch,
                                              float* __restrict__ poolsum) {
  int dst = blockIdx.x, t = threadIdx.x;
  int beg = rowptr[dst], deg = rowptr[dst + 1] - beg;
  float adv = ad2[dst];
  __shared__ float red[2];
  // max
  float pm = -1e30f;
  for (int e = t; e < deg; e += 128) {
    float v = as2[csr[beg + e]] + adv;
    v = v > 0.f ? v : NEG_SLOPE * v;
    pm = fmaxf(pm, v);
  }
  #pragma unroll
  for (int off = 32; off; off >>= 1) pm = fmaxf(pm, __shfl_down(pm, off));
  if ((t & 63) == 0) red[t >> 6] = pm;
  __syncthreads();
  float m = fmaxf(red[0], red[1]);
  // sum
  float ps = 0.f;
  for (int e = t; e < deg; e += 128) {
    float v = as2[csr[beg + e]] + adv;
    v = v > 0.f ? v : NEG_SLOPE * v;
    ps += __expf(v - m);
  }
  __syncthreads();
  #pragma unroll
  for (int off = 32; off; off >>= 1) ps += __shfl_down(ps, off);
  if ((t & 63) == 0) red[t >> 6] = ps;
  __syncthreads();
  float inv = 1.0f / (red[0] + red[1] + EPS);
  // aggregate
  __shared__ float al[128];
  __shared__ int ss[128];
  float acc = 0.f;
  for (int base = 0; base < deg; base += 128) {
    int nn = min(128, deg - base);
    __syncthreads();
    if (t < nn) {
      int s = csr[beg + base + t];
      ss[t] = s;
      float v = as2[s] + adv;
      v = v > 0.f ? v : NEG_SLOPE * v;
      al[t] = __expf(v - m) * inv;
    }
    __syncthreads();
    for (int e = 0; e < nn; e++)
      acc = fmaf(al[e], xl2[(size_t)ss[e] * 128 + t], acc);
  }
  float v = acc + b2[t];
  v = v > 0.f ? v : (expf(v) - 1.0f);  // ELU
  atomicAdd(&poolsum[batch[dst] * 128 + t], v);
}

__global__ void count_k(const int* __restrict__ batch, int* __restrict__ cnt) {
  int n = blockIdx.x * blockDim.x + threadIdx.x;
  if (n < N_NODES) atomicAdd(&cnt[batch[n]], 1);
}

// ---------------- pooled MLP head: out[g] = lin2(relu(lin1(pooled))) ----------------
__global__ __launch_bounds__(128) void final_k(const float* __restrict__ poolsum,
                                               const int* __restrict__ cnt,
                                               const float* __restrict__ l1w,
                                               const float* __restrict__ l1b,
                                               const float* __restrict__ l2w,
                                               const float* __restrict__ l2b,
                                               float* __restrict__ out) {
  int g = blockIdx.x, t = threadIdx.x;
  __shared__ float pooled[128];
  float c = fmaxf((float)cnt[g], 1.0f);
  pooled[t] = poolsum[g * 128 + t] / c;
  __syncthreads();
  float acc = l1b[t];
  for (int i = 0; i < 128; i++) acc = fmaf(pooled[i], l1w[i * 128 + t], acc);
  acc = fmaxf(acc, 0.0f);  // ReLU
  float p = acc * l2w[t];
  #pragma unroll
  for (int off = 32; off; off >>= 1) p += __shfl_down(p, off);
  __shared__ float r[2];
  if ((t & 63) == 0) r[t >> 6] = p;
  __syncthreads();
  if (t == 0) out[g] = r[0] + r[1] + l2b[0];
}

extern "C" void kernel_launch(void* const* d_in, const int* in_sizes, int n_in,
                              void* d_out, int out_size, void* d_ws, size_t ws_size,
                              hipStream_t stream) {
  const float* x    = (const float*)d_in[0];
  const int*   ei   = (const int*)d_in[1];   // [2, 320000] int32
  const int*   batch= (const int*)d_in[2];
  const float* W1   = (const float*)d_in[3];
  const float* aS1  = (const float*)d_in[4];
  const float* aD1  = (const float*)d_in[5];
  const float* b1   = (const float*)d_in[6];
  const float* W2   = (const float*)d_in[7];
  const float* aS2  = (const float*)d_in[8];
  const float* aD2  = (const float*)d_in[9];
  const float* b2   = (const float*)d_in[10];
  const float* l1w  = (const float*)d_in[11];
  const float* l1b  = (const float*)d_in[12];
  const float* l2w  = (const float*)d_in[13];
  const float* l2b  = (const float*)d_in[14];
  float* out = (float*)d_out;

  float* ws      = (float*)d_ws;
  float* xl1     = ws;                        // 10,240,000 f
  float* h1      = xl1 + 10240000;            // 10,240,000 f
  float* as1     = h1 + 10240000;             // 80,000 f
  float* ad1     = as1 + 80000;               // 80,000 f
  float* as2     = ad1 + 80000;               // 10,000 f
  float* ad2     = as2 + 10000;               // 10,000 f
  float* poolsum = ad2 + 10000;               // 8,192 f
  int*   poolcnt = (int*)(poolsum + 8192);    // 64 i
  int*   deg     = poolcnt + 64;              // 10,000 i
  int*   rowptr  = deg + 10000;               // 10,001 i
  int*   wof     = rowptr + 10001;            // 10,000 i
  int*   csr     = wof + 10000;               // 330,000 i
  float* xl2     = xl1;                       // alias: xl1 dead after agg1

  hipMemsetAsync(deg, 0, N_NODES * sizeof(int), stream);
  hipMemsetAsync(poolsum, 0, N_GRAPHS * 128 * sizeof(float), stream);
  hipMemsetAsync(poolcnt, 0, N_GRAPHS * sizeof(int), stream);

  // layer 1
  gemm_k<<<dim3(16, 157), 256, 0, stream>>>(x, W1, xl1, N_NODES, 1024, 128);
  attn1_k<<<N_NODES, 256, 0, stream>>>(xl1, aS1, aD1, as1, ad1);
  int eb = (E_ALL + 255) / 256;
  degree_k<<<eb, 256, 0, stream>>>(ei, deg);
  scan_k<<<1, 1024, 0, stream>>>(deg, rowptr, wof);
  fill_k<<<eb, 256, 0, stream>>>(ei, wof, csr);
  agg1_k<<<N_NODES, 256, 0, stream>>>(xl1, as1, ad1, b1, rowptr, csr, h1);
  // layer 2
  gemm_k<<<dim3(2, 157), 256, 0, stream>>>(h1, W2, xl2, N_NODES, 128, 1024);
  attn2_k<<<N_NODES, 128, 0, stream>>>(xl2, aS2, aD2, as2, ad2);
  agg2_k<<<N_NODES, 128, 0, stream>>>(xl2, as2, ad2, b2, rowptr, csr, batch, poolsum);
  // head
  count_k<<<(N_NODES + 255) / 256, 256, 0, stream>>>(batch, poolcnt);
  final_k<<<N_GRAPHS, 128, 0, stream>>>(poolsum, poolcnt, l1w, l1b, l2w, l2b, out);
}

// Round 2
// 400.197 us; speedup vs baseline: 1.2790x; 1.2790x over previous
//
#include <hip/hip_runtime.h>
#include <math.h>

#define N_NODES 10000
#define N_GRAPHS 64
#define E_RAW 320000
#define E_ALL (E_RAW + N_NODES)   // 330000 edges incl. self-loops
#define NEG_SLOPE 0.2f
#define EPS 1e-16f

typedef unsigned short ushort_t;

static __device__ __forceinline__ float bfl(unsigned u) {
  union { unsigned u; float f; } v; v.u = u << 16; return v.f;
}
static __device__ __forceinline__ float bfh(unsigned u) {
  union { unsigned u; float f; } v; v.u = u & 0xFFFF0000u; return v.f;
}
static __device__ __forceinline__ ushort_t f2bf(float f) {  // RNE
  union { float f; unsigned u; } v; v.f = f;
  unsigned r = v.u + 0x7FFFu + ((v.u >> 16) & 1u);
  return (ushort_t)(r >> 16);
}

// ---------------- f32 tiled GEMM with fused epilogue ----------------
// C[M,N] = A[M,K] @ B[K,N]; 64x64 tile, BK=64, 256 thr, 4x4 micro-tile.
// Epilogue: optional bf16 store (Cb) and fused GAT attention logits:
//   asO[r,h] += sum_c acc[r,c]*aS[h,c] (h = col>>7), same for adO.  (f32, atomics)
__global__ __launch_bounds__(256) void gemm_k(const float* __restrict__ A,
                                              const float* __restrict__ B,
                                              ushort_t* __restrict__ Cb,
                                              const float* __restrict__ aS,
                                              const float* __restrict__ aD,
                                              float* __restrict__ asO,
                                              float* __restrict__ adO,
                                              int M, int N, int K) {
  __shared__ float As[64][68];
  __shared__ float Bs[64][68];
  const int m0 = blockIdx.y * 64, n0 = blockIdx.x * 64;
  const int t = threadIdx.x, tx = t & 15, ty = t >> 4;
  float acc[4][4] = {};
  for (int kk = 0; kk < K; kk += 64) {
    #pragma unroll
    for (int i = 0; i < 4; i++) {
      int f = t + 256 * i;
      int row = f >> 4, k4 = f & 15;
      float4 v = make_float4(0.f, 0.f, 0.f, 0.f);
      int gr = m0 + row;
      if (gr < M) v = *(const float4*)(A + (size_t)gr * K + kk + 4 * k4);
      *(float4*)(&As[row][4 * k4]) = v;
    }
    #pragma unroll
    for (int i = 0; i < 4; i++) {
      int f = t + 256 * i;
      int k = f >> 4, c4 = f & 15;
      float4 v = *(const float4*)(B + (size_t)(kk + k) * N + n0 + 4 * c4);
      *(float4*)(&Bs[k][4 * c4]) = v;
    }
    __syncthreads();
    #pragma unroll
    for (int k = 0; k < 64; k++) {
      float4 b = *(const float4*)(&Bs[k][tx * 4]);
      float a0 = As[ty * 4 + 0][k];
      float a1 = As[ty * 4 + 1][k];
      float a2 = As[ty * 4 + 2][k];
      float a3 = As[ty * 4 + 3][k];
      acc[0][0] = fmaf(a0, b.x, acc[0][0]); acc[0][1] = fmaf(a0, b.y, acc[0][1]);
      acc[0][2] = fmaf(a0, b.z, acc[0][2]); acc[0][3] = fmaf(a0, b.w, acc[0][3]);
      acc[1][0] = fmaf(a1, b.x, acc[1][0]); acc[1][1] = fmaf(a1, b.y, acc[1][1]);
      acc[1][2] = fmaf(a1, b.z, acc[1][2]); acc[1][3] = fmaf(a1, b.w, acc[1][3]);
      acc[2][0] = fmaf(a2, b.x, acc[2][0]); acc[2][1] = fmaf(a2, b.y, acc[2][1]);
      acc[2][2] = fmaf(a2, b.z, acc[2][2]); acc[2][3] = fmaf(a2, b.w, acc[2][3]);
      acc[3][0] = fmaf(a3, b.x, acc[3][0]); acc[3][1] = fmaf(a3, b.y, acc[3][1]);
      acc[3][2] = fmaf(a3, b.z, acc[3][2]); acc[3][3] = fmaf(a3, b.w, acc[3][3]);
    }
    __syncthreads();
  }
  const int Hh = N >> 7;               // heads (N = H*128)
  const int col0 = n0 + tx * 4;
  const int h = col0 >> 7, cb = col0 & 127;
  #pragma unroll
  for (int i = 0; i < 4; i++) {
    int gr = m0 + ty * 4 + i;
    bool ok = gr < M;
    if (ok) {
      ushort4 bv;
      bv.x = f2bf(acc[i][0]); bv.y = f2bf(acc[i][1]);
      bv.z = f2bf(acc[i][2]); bv.w = f2bf(acc[i][3]);
      *(ushort4*)(Cb + (size_t)gr * N + col0) = bv;
    }
    // fused attention logits (f32 precision)
    float sp = 0.f, dp = 0.f;
    #pragma unroll
    for (int c = 0; c < 4; c++) {
      sp = fmaf(acc[i][c], aS[h * 128 + cb + c], sp);
      dp = fmaf(acc[i][c], aD[h * 128 + cb + c], dp);
    }
    #pragma unroll
    for (int off = 8; off; off >>= 1) {
      sp += __shfl_down(sp, off, 16);
      dp += __shfl_down(dp, off, 16);
    }
    if (tx == 0 && ok) {
      atomicAdd(&asO[gr * Hh + h], sp);
      atomicAdd(&adO[gr * Hh + h], dp);
    }
  }
}

// ---------------- CSR build ----------------
__global__ void degree_k(const int* __restrict__ ei, int* __restrict__ deg) {
  int e = blockIdx.x * blockDim.x + threadIdx.x;
  if (e >= E_ALL) return;
  int d = (e < E_RAW) ? ei[E_RAW + e] : (e - E_RAW);
  atomicAdd(&deg[d], 1);
}

__global__ __launch_bounds__(1024) void scan_k(const int* __restrict__ deg,
                                               int* __restrict__ rowptr,
                                               int* __restrict__ wof) {
  __shared__ int part[1024];
  int t = threadIdx.x;
  int base = t * 10;
  int local[10];
  int s = 0;
  #pragma unroll
  for (int i = 0; i < 10; i++) {
    int idx = base + i;
    local[i] = s;
    s += (idx < N_NODES) ? deg[idx] : 0;
  }
  part[t] = s;
  __syncthreads();
  for (int off = 1; off < 1024; off <<= 1) {
    int v = (t >= off) ? part[t - off] : 0;
    __syncthreads();
    part[t] += v;
    __syncthreads();
  }
  int pre = t ? part[t - 1] : 0;
  #pragma unroll
  for (int i = 0; i < 10; i++) {
    int idx = base + i;
    if (idx < N_NODES) {
      int val = pre + local[i];
      rowptr[idx] = val;
      wof[idx] = val;
    }
  }
  if (t == 1023) rowptr[N_NODES] = part[1023];
}

__global__ void fill_k(const int* __restrict__ ei, int* __restrict__ wof,
                       int* __restrict__ csr) {
  int e = blockIdx.x * blockDim.x + threadIdx.x;
  if (e >= E_ALL) return;
  int s, d;
  if (e < E_RAW) { s = ei[e]; d = ei[E_RAW + e]; }
  else           { s = d = e - E_RAW; }
  int pos = atomicAdd(&wof[d], 1);
  csr[pos] = s;
}

// ---------------- layer-1 softmax + aggregation + bias + ELU ----------------
// one block (128 thr) per dst. Thread t owns channels 8t..8t+7 (head t>>4).
// Gathers bf16 rows as uint4 (16 B/lane).
__global__ __launch_bounds__(128) void agg1_k(const ushort_t* __restrict__ xlb,
                                              const float* __restrict__ as1,
                                              const float* __restrict__ ad1,
                                              const float* __restrict__ b1,
                                              const int* __restrict__ rowptr,
                                              const int* __restrict__ csr,
                                              float* __restrict__ out) {
  int dst = blockIdx.x, t = threadIdx.x;
  int beg = rowptr[dst], deg = rowptr[dst + 1] - beg;
  int h2 = t & 7, slot = t >> 3;   // stats mapping: 16 slots x 8 heads
  int h = t >> 4;                  // aggregation head of channels 8t..8t+7
  float adh2 = ad1[dst * 8 + h2];
  __shared__ float sred[8][17];
  __shared__ float mh[8], sh[8];
  // pass 1: per-head max of leaky_relu logits
  float pm = -1e30f;
  for (int e = slot; e < deg; e += 16) {
    float v = as1[csr[beg + e] * 8 + h2] + adh2;
    v = v > 0.f ? v : NEG_SLOPE * v;
    pm = fmaxf(pm, v);
  }
  sred[h2][slot] = pm;
  __syncthreads();
  if (t < 8) {
    float m = sred[t][0];
    for (int i = 1; i < 16; i++) m = fmaxf(m, sred[t][i]);
    mh[t] = m;
  }
  __syncthreads();
  float m2 = mh[h2];
  // pass 2: per-head sum of exp
  float ps = 0.f;
  for (int e = slot; e < deg; e += 16) {
    float v = as1[csr[beg + e] * 8 + h2] + adh2;
    v = v > 0.f ? v : NEG_SLOPE * v;
    ps += __expf(v - m2);
  }
  __syncthreads();
  sred[h2][slot] = ps;
  __syncthreads();
  if (t < 8) {
    float s = 0.f;
    for (int i = 0; i < 16; i++) s += sred[t][i];
    sh[t] = 1.0f / (s + EPS);
  }
  __syncthreads();
  float inv2 = sh[h2];
  // pass 3: weighted aggregation, 16-edge chunks, alpha staged in LDS
  __shared__ float al[16][9];
  __shared__ int ss[16];
  float acc[8] = {};
  for (int base = 0; base < deg; base += 16) {
    int nn = min(16, deg - base);
    __syncthreads();
    if (slot < nn) {
      int s = csr[beg + base + slot];
      if (h2 == 0) ss[slot] = s;
      float v = as1[s * 8 + h2] + adh2;
      v = v > 0.f ? v : NEG_SLOPE * v;
      al[slot][h2] = __expf(v - m2) * inv2;
    }
    __syncthreads();
    #pragma unroll 4
    for (int e = 0; e < nn; e++) {
      float a = al[e][h];
      const uint4 u = *(const uint4*)(xlb + (size_t)ss[e] * 1024 + 8 * t);
      acc[0] = fmaf(a, bfl(u.x), acc[0]); acc[1] = fmaf(a, bfh(u.x), acc[1]);
      acc[2] = fmaf(a, bfl(u.y), acc[2]); acc[3] = fmaf(a, bfh(u.y), acc[3]);
      acc[4] = fmaf(a, bfl(u.z), acc[4]); acc[5] = fmaf(a, bfh(u.z), acc[5]);
      acc[6] = fmaf(a, bfl(u.w), acc[6]); acc[7] = fmaf(a, bfh(u.w), acc[7]);
    }
  }
  #pragma unroll
  for (int j = 0; j < 8; j++) {
    int o = 8 * t + j;
    float v = acc[j] + b1[o];
    v = v > 0.f ? v : (expf(v) - 1.0f);  // ELU
    out[(size_t)dst * 1024 + o] = v;
  }
}

// ---------------- layer-2 softmax + aggregation + bias + ELU + pooling ----------------
// one wave (64 thr) per dst. H=1, C=128; thread t owns channels 2t, 2t+1.
__global__ __launch_bounds__(64) void agg2_k(const ushort_t* __restrict__ xlb2,
                                             const float* __restrict__ as2,
                                             const float* __restrict__ ad2,
                                             const float* __restrict__ b2,
                                             const int* __restrict__ rowptr,
                                             const int* __restrict__ csr,
                                             const int* __restrict__ batch,
                                             float* __restrict__ poolsum) {
  int dst = blockIdx.x, t = threadIdx.x;
  int beg = rowptr[dst], deg = rowptr[dst + 1] - beg;
  float adv = ad2[dst];
  // max (butterfly over 64 lanes)
  float pm = -1e30f;
  for (int e = t; e < deg; e += 64) {
    float v = as2[csr[beg + e]] + adv;
    v = v > 0.f ? v : NEG_SLOPE * v;
    pm = fmaxf(pm, v);
  }
  #pragma unroll
  for (int off = 32; off; off >>= 1) pm = fmaxf(pm, __shfl_xor(pm, off));
  float m = pm;
  // sum
  float ps = 0.f;
  for (int e = t; e < deg; e += 64) {
    float v = as2[csr[beg + e]] + adv;
    v = v > 0.f ? v : NEG_SLOPE * v;
    ps += __expf(v - m);
  }
  #pragma unroll
  for (int off = 32; off; off >>= 1) ps += __shfl_xor(ps, off);
  float inv = 1.0f / (ps + EPS);
  // aggregate, 64-edge chunks
  __shared__ float al[64];
  __shared__ int ss[64];
  float acc0 = 0.f, acc1 = 0.f;
  for (int base = 0; base < deg; base += 64) {
    int nn = min(64, deg - base);
    __syncthreads();
    if (t < nn) {
      int s = csr[beg + base + t];
      ss[t] = s;
      float v = as2[s] + adv;
      v = v > 0.f ? v : NEG_SLOPE * v;
      al[t] = __expf(v - m) * inv;
    }
    __syncthreads();
    #pragma unroll 4
    for (int e = 0; e < nn; e++) {
      unsigned u = *(const unsigned*)(xlb2 + (size_t)ss[e] * 128 + 2 * t);
      acc0 = fmaf(al[e], bfl(u), acc0);
      acc1 = fmaf(al[e], bfh(u), acc1);
    }
  }
  int c0 = 2 * t;
  float v0 = acc0 + b2[c0];
  float v1 = acc1 + b2[c0 + 1];
  v0 = v0 > 0.f ? v0 : (expf(v0) - 1.0f);
  v1 = v1 > 0.f ? v1 : (expf(v1) - 1.0f);
  int g = batch[dst];
  atomicAdd(&poolsum[g * 128 + c0], v0);
  atomicAdd(&poolsum[g * 128 + c0 + 1], v1);
}

__global__ void count_k(const int* __restrict__ batch, int* __restrict__ cnt) {
  int n = blockIdx.x * blockDim.x + threadIdx.x;
  if (n < N_NODES) atomicAdd(&cnt[batch[n]], 1);
}

// ---------------- pooled MLP head ----------------
__global__ __launch_bounds__(128) void final_k(const float* __restrict__ poolsum,
                                               const int* __restrict__ cnt,
                                               const float* __restrict__ l1w,
                                               const float* __restrict__ l1b,
                                               const float* __restrict__ l2w,
                                               const float* __restrict__ l2b,
                                               float* __restrict__ out) {
  int g = blockIdx.x, t = threadIdx.x;
  __shared__ float pooled[128];
  float c = fmaxf((float)cnt[g], 1.0f);
  pooled[t] = poolsum[g * 128 + t] / c;
  __syncthreads();
  float acc = l1b[t];
  for (int i = 0; i < 128; i++) acc = fmaf(pooled[i], l1w[i * 128 + t], acc);
  acc = fmaxf(acc, 0.0f);  // ReLU
  float p = acc * l2w[t];
  #pragma unroll
  for (int off = 32; off; off >>= 1) p += __shfl_down(p, off);
  __shared__ float r[2];
  if ((t & 63) == 0) r[t >> 6] = p;
  __syncthreads();
  if (t == 0) out[g] = r[0] + r[1] + l2b[0];
}

extern "C" void kernel_launch(void* const* d_in, const int* in_sizes, int n_in,
                              void* d_out, int out_size, void* d_ws, size_t ws_size,
                              hipStream_t stream) {
  const float* x    = (const float*)d_in[0];
  const int*   ei   = (const int*)d_in[1];
  const int*   batch= (const int*)d_in[2];
  const float* W1   = (const float*)d_in[3];
  const float* aS1  = (const float*)d_in[4];
  const float* aD1  = (const float*)d_in[5];
  const float* b1   = (const float*)d_in[6];
  const float* W2   = (const float*)d_in[7];
  const float* aS2  = (const float*)d_in[8];
  const float* aD2  = (const float*)d_in[9];
  const float* b2   = (const float*)d_in[10];
  const float* l1w  = (const float*)d_in[11];
  const float* l1b  = (const float*)d_in[12];
  const float* l2w  = (const float*)d_in[13];
  const float* l2b  = (const float*)d_in[14];
  float* out = (float*)d_out;

  // workspace layout (total ~66 MB)
  float*    h1     = (float*)d_ws;                    // 10,240,000 f  (layer-1 output, f32)
  ushort_t* xlb1   = (ushort_t*)(h1 + 10240000);      // 10,240,000 bf16
  ushort_t* xlb2   = xlb1 + 10240000;                 // 1,280,000 bf16
  float*    zero0  = (float*)(xlb2 + 1280000);        // ---- zero block start ----
  float*    as1    = zero0;                           // 80,000 f
  float*    ad1    = as1 + 80000;                     // 80,000 f
  float*    as2    = ad1 + 80000;                     // 10,000 f
  float*    ad2    = as2 + 10000;                     // 10,000 f
  float*    poolsum= ad2 + 10000;                     // 8,192 f
  int*      poolcnt= (int*)(poolsum + 8192);          // 64 i
  int*      deg    = poolcnt + 64;                    // 10,000 i  ---- zero block end ----
  int*      rowptr = deg + 10000;                     // 10,001 i
  int*      wof    = rowptr + 10001;                  // 10,000 i
  int*      csr    = wof + 10000;                     // 330,000 i

  size_t zero_elems = 80000 + 80000 + 10000 + 10000 + 8192 + 64 + 10000;
  hipMemsetAsync(zero0, 0, zero_elems * 4, stream);

  // CSR build
  int eb = (E_ALL + 255) / 256;
  degree_k<<<eb, 256, 0, stream>>>(ei, deg);
  scan_k<<<1, 1024, 0, stream>>>(deg, rowptr, wof);
  fill_k<<<eb, 256, 0, stream>>>(ei, wof, csr);

  // layer 1: GEMM (+ fused logits), then softmax-aggregate
  gemm_k<<<dim3(16, 157), 256, 0, stream>>>(x, W1, xlb1, aS1, aD1, as1, ad1,
                                            N_NODES, 1024, 128);
  agg1_k<<<N_NODES, 128, 0, stream>>>(xlb1, as1, ad1, b1, rowptr, csr, h1);

  // layer 2
  gemm_k<<<dim3(2, 157), 256, 0, stream>>>(h1, W2, xlb2, aS2, aD2, as2, ad2,
                                           N_NODES, 128, 1024);
  agg2_k<<<N_NODES, 64, 0, stream>>>(xlb2, as2, ad2, b2, rowptr, csr, batch, poolsum);

  // head
  count_k<<<(N_NODES + 255) / 256, 256, 0, stream>>>(batch, poolcnt);
  final_k<<<N_GRAPHS, 128, 0, stream>>>(poolsum, poolcnt, l1w, l1b, l2w, l2b, out);
}